// Round 4
// baseline (130.099 us; speedup 1.0000x reference)
//
#include <hip/hip_runtime.h>
#include <math.h>

#define B 8
#define N 2048
#define NP1 2049
#define FIN 128
#define FOUT 64
#define NS 0.2f
#define NCH 64
#define CHS 32

typedef unsigned long long u64;

__device__ __forceinline__ unsigned f2u(float f) {
  unsigned u = __float_as_uint(f);
  return (u & 0x80000000u) ? ~u : (u | 0x80000000u);
}
__device__ __forceinline__ float u2f(unsigned v) {
  unsigned u = (v & 0x80000000u) ? (v ^ 0x80000000u) : ~v;
  return __uint_as_float(u);
}

// ---------------------------------------------------------------------------
// KA: h = x@W, s1 = h.a1, s2 = h.a2, exps.
// W column f cached in 128 VGPRs/thread; x staged in LDS; wave = 8 rows.
// grid = 512 blocks x 256 threads (block = 32 rows).
// ---------------------------------------------------------------------------
#define RPB 32
__global__ __launch_bounds__(256, 2) void k_hs(
    const float* __restrict__ x, const float* __restrict__ W,
    const float* __restrict__ a, float* __restrict__ h,
    float* __restrict__ s1, float* __restrict__ s2,
    float* __restrict__ u, float* __restrict__ uq,
    float* __restrict__ e2, float* __restrict__ eq2) {
  __shared__ float xs[RPB * FIN];  // 16 KB
  const int row0 = blockIdx.x * RPB;
  const int lane = threadIdx.x & 63;
  const int wv = threadIdx.x >> 6;

  // cooperative x stage: 1024 float4
  {
    const float4* src = (const float4*)(x + (size_t)row0 * FIN);
    float4* dst = (float4*)xs;
#pragma unroll
    for (int t = 0; t < 4; ++t)
      dst[threadIdx.x + 256 * t] = src[threadIdx.x + 256 * t];
  }

  // W column -> registers (coalesced 256B per k, L1-hot)
  float w[FIN];
#pragma unroll
  for (int k = 0; k < FIN; ++k) w[k] = W[k * FOUT + lane];
  const float a1 = a[lane];
  const float a2 = a[FOUT + lane];
  __syncthreads();

  for (int n = 0; n < 8; ++n) {
    const int r = wv * 8 + n;
    const float* xr = xs + r * FIN;
    float ac0 = 0.f, ac1 = 0.f, ac2 = 0.f, ac3 = 0.f;
#pragma unroll
    for (int k4 = 0; k4 < FIN; k4 += 4) {
      float4 xv = *(const float4*)(xr + k4);
      ac0 = fmaf(xv.x, w[k4 + 0], ac0);
      ac1 = fmaf(xv.y, w[k4 + 1], ac1);
      ac2 = fmaf(xv.z, w[k4 + 2], ac2);
      ac3 = fmaf(xv.w, w[k4 + 3], ac3);
    }
    const float acc = (ac0 + ac1) + (ac2 + ac3);
    const int row = row0 + r;
    h[(size_t)row * FOUT + lane] = acc;

    float v1 = acc * a1;
    float v2 = acc * a2;
#pragma unroll
    for (int off = 32; off > 0; off >>= 1) {
      v1 += __shfl_xor(v1, off, 64);
      v2 += __shfl_xor(v2, off, 64);
    }
    if (lane == 0) {
      s1[row] = v1;
      s2[row] = v2;
      u[row] = expf(v1);
      uq[row] = expf(NS * v1);
      e2[row] = expf(v2);
      eq2[row] = expf(NS * v2);
    }
  }
}

// ---------------------------------------------------------------------------
// KB: per (batch, type): bitonic sort 2048 (key|idx) in LDS (256 threads).
// type 1: key = s2 -> write s2s, idx2.
// type 0: key = s1 -> inclusive scans of u,uq in sorted order, then for every
//         j: binary-search c = #{s1 < -s2_j}; Z; A_j = e2/Z, Bc_j = eq2/Z.
// grid = 2*B blocks of 256 threads.
// ---------------------------------------------------------------------------
__global__ __launch_bounds__(256) void k_sortz(
    const float* __restrict__ s1, const float* __restrict__ s2,
    const float* __restrict__ u, const float* __restrict__ uq,
    const float* __restrict__ e2, const float* __restrict__ eq2,
    float* __restrict__ A, float* __restrict__ Bc,
    float* __restrict__ s2s, int* __restrict__ idx2) {
  __shared__ u64 keys[N];    // 16 KB
  __shared__ float sU[N];    // 8 KB
  __shared__ float sQ[N];    // 8 KB
  __shared__ float s1v[N];   // 8 KB
  const int type = blockIdx.x & 1;
  const int b = blockIdx.x >> 1;
  const int tid = threadIdx.x;
  const float* ksrc = type ? s2 : s1;

  for (int t = tid; t < N; t += 256)
    keys[t] = ((u64)f2u(ksrc[b * N + t]) << 32) | (unsigned)t;
  __syncthreads();

  for (int k = 2; k <= N; k <<= 1) {
    for (int j = k >> 1; j > 0; j >>= 1) {
      for (int t = tid; t < N; t += 256) {
        int p = t ^ j;
        if (p > t) {
          u64 av = keys[t], cv = keys[p];
          bool asc = ((t & k) == 0);
          if ((av > cv) == asc) { keys[t] = cv; keys[p] = av; }
        }
      }
      __syncthreads();
    }
  }

  if (type == 1) {
    for (int t = tid; t < N; t += 256) {
      u64 kv = keys[t];
      s2s[b * N + t] = u2f((unsigned)(kv >> 32));
      idx2[b * N + t] = (int)(kv & 0xffffffffu);
    }
    return;
  }

  for (int t = tid; t < N; t += 256) {
    u64 kv = keys[t];
    s1v[t] = u2f((unsigned)(kv >> 32));
    int idx = (int)(kv & 0xffffffffu);
    sU[t] = u[b * N + idx];
    sQ[t] = uq[b * N + idx];
  }
  __syncthreads();

  // inclusive Hillis-Steele scan, 8 elements per thread
  for (int off = 1; off < N; off <<= 1) {
    float tu[8], tq[8];
    int c = 0;
    for (int t = tid; t < N; t += 256, ++c) {
      tu[c] = sU[t] + (t >= off ? sU[t - off] : 0.f);
      tq[c] = sQ[t] + (t >= off ? sQ[t - off] : 0.f);
    }
    __syncthreads();
    c = 0;
    for (int t = tid; t < N; t += 256, ++c) {
      sU[t] = tu[c];
      sQ[t] = tq[c];
    }
    __syncthreads();
  }

  const float totU = sU[N - 1];
  for (int jj = tid; jj < N; jj += 256) {
    const float thr = -s2[b * N + jj];
    int lo = 0, hi = N;
#pragma unroll
    for (int it = 0; it < 11; ++it) {
      int mid = (lo + hi) >> 1;
      if (s1v[mid] < thr) lo = mid + 1; else hi = mid;
    }
    const int c = lo;
    const float PuC = c ? sU[c - 1] : 0.f;
    const float PqC = c ? sQ[c - 1] : 0.f;
    const float E = e2[b * N + jj];
    const float Eq = eq2[b * N + jj];
    const float Z = E * (totU - PuC) + Eq * PqC;
    A[b * N + jj] = E / Z;
    Bc[b * N + jj] = Eq / Z;
  }
}

// ---------------------------------------------------------------------------
// KC: chunk totals of A*h, B*h in s2-sorted order. wave = one chunk of 32.
// grid = B*16 blocks of 256 threads (4 waves).
// ---------------------------------------------------------------------------
__global__ void k_scan1(const float* __restrict__ A, const float* __restrict__ Bc,
                        const float* __restrict__ h, const int* __restrict__ idx2,
                        float* __restrict__ ctA, float* __restrict__ ctB) {
  const int b = blockIdx.x >> 4;
  const int chunk = (blockIdx.x & 15) * 4 + (threadIdx.x >> 6);
  const int f = threadIdx.x & 63;
  float ta = 0.f, tb = 0.f;
#pragma unroll 4
  for (int rr = 0; rr < CHS; ++rr) {
    const int r = chunk * CHS + rr;
    const int j = idx2[b * N + r];
    const float hv = h[((size_t)b * N + j) * FOUT + f];
    ta = fmaf(A[b * N + j], hv, ta);
    tb = fmaf(Bc[b * N + j], hv, tb);
  }
  ctA[(b * NCH + chunk) * FOUT + f] = ta;
  ctB[(b * NCH + chunk) * FOUT + f] = tb;
}

// ---------------------------------------------------------------------------
// KD: PB[c][f] = prefix of B*h (ranks < c), SA[c][f] = suffix of A*h.
// Chunk totals staged in LDS. wave = one chunk. grid = B*16 x 256.
// ---------------------------------------------------------------------------
__global__ void k_scan2(const float* __restrict__ A, const float* __restrict__ Bc,
                        const float* __restrict__ h, const int* __restrict__ idx2,
                        const float* __restrict__ ctA, const float* __restrict__ ctB,
                        float* __restrict__ SA, float* __restrict__ PB) {
  __shared__ float cA[NCH * FOUT];  // 16 KB
  __shared__ float cB[NCH * FOUT];  // 16 KB
  const int b = blockIdx.x >> 4;
  const int chunk = (blockIdx.x & 15) * 4 + (threadIdx.x >> 6);
  const int f = threadIdx.x & 63;

  for (int t = threadIdx.x; t < NCH * FOUT; t += 256) {
    cA[t] = ctA[b * NCH * FOUT + t];
    cB[t] = ctB[b * NCH * FOUT + t];
  }
  __syncthreads();

  float offA = 0.f, offB = 0.f;
#pragma unroll 8
  for (int c2 = 0; c2 < NCH; ++c2) {
    const float va = cA[c2 * FOUT + f];
    const float vb = cB[c2 * FOUT + f];
    if (c2 > chunk) offA += va;
    if (c2 < chunk) offB += vb;
  }

  float run = offB;
  for (int rr = 0; rr < CHS; ++rr) {
    const int r = chunk * CHS + rr;
    const int j = idx2[b * N + r];
    const float hv = h[((size_t)b * N + j) * FOUT + f];
    run = fmaf(Bc[b * N + j], hv, run);
    PB[((size_t)b * NP1 + r + 1) * FOUT + f] = run;
  }
  run = offA;
  for (int rr = CHS - 1; rr >= 0; --rr) {
    const int r = chunk * CHS + rr;
    const int j = idx2[b * N + r];
    const float hv = h[((size_t)b * N + j) * FOUT + f];
    run = fmaf(A[b * N + j], hv, run);
    SA[((size_t)b * NP1 + r) * FOUT + f] = run;
  }
  if (chunk == 0) {
    PB[((size_t)b * NP1 + 0) * FOUT + f] = 0.f;
    SA[((size_t)b * NP1 + N) * FOUT + f] = 0.f;
  }
}

// ---------------------------------------------------------------------------
// KE: per row i: wave-ballot lower_bound(s2s, -s1_i) -> c;
//     out[f] = lrelu(u_i*SA[c][f] + uq_i*PB[c][f]).
// grid = B*N/4 blocks of 256 (one row per wave).
// ---------------------------------------------------------------------------
__global__ void k_out(const float* __restrict__ s1, const float* __restrict__ u,
                      const float* __restrict__ uq, const float* __restrict__ s2s,
                      const float* __restrict__ SA, const float* __restrict__ PB,
                      float* __restrict__ out) {
  const int wv = threadIdx.x >> 6;
  const int lane = threadIdx.x & 63;
  const int row = blockIdx.x * 4 + wv;
  const int b = row >> 11;
  const float t = -s1[row];
  const float* ks = s2s + b * N;

  const float v0 = ks[lane * 32];
  const unsigned long long m = __ballot(v0 < t);
  const int m1 = __popcll(m);
  int c;
  if (m1 == 0) {
    c = 0;
  } else {
    const int base = (m1 - 1) * 32;
    const float v1 = ks[base + (lane & 31)];
    const unsigned long long m2 = __ballot((lane < 32) && (v1 < t));
    c = base + __popcll(m2);
  }
  const float sa = SA[((size_t)b * NP1 + c) * FOUT + lane];
  const float pb = PB[((size_t)b * NP1 + c) * FOUT + lane];
  const float v = u[row] * sa + uq[row] * pb;
  out[(size_t)row * FOUT + lane] = v >= 0.f ? v : NS * v;
}

extern "C" void kernel_launch(void* const* d_in, const int* in_sizes, int n_in,
                              void* d_out, int out_size, void* d_ws, size_t ws_size,
                              hipStream_t stream) {
  const float* x = (const float*)d_in[0];   // (8,2048,128)
  const float* W = (const float*)d_in[1];   // (128,64)
  const float* a = (const float*)d_in[2];   // (128,1)
  float* out = (float*)d_out;               // (8,2048,64)

  // h lives in d_out as scratch; consumed by k_scan1/k_scan2 before k_out
  // overwrites d_out with the final result.
  float* h = out;

  float* ws = (float*)d_ws;
  float* s1 = ws;                 // B*N each
  float* s2 = s1 + B * N;
  float* u = s2 + B * N;
  float* uq = u + B * N;
  float* e2 = uq + B * N;
  float* eq2 = e2 + B * N;
  float* A = eq2 + B * N;
  float* Bc = A + B * N;
  float* s2s = Bc + B * N;
  int* idx2 = (int*)(s2s + B * N);
  float* ctA = (float*)(idx2 + B * N);  // B*64*64
  float* ctB = ctA + B * NCH * FOUT;
  float* SA = ctB + B * NCH * FOUT;     // B*(N+1)*64
  float* PB = SA + (size_t)B * NP1 * FOUT;

  k_hs<<<B * N / RPB, 256, 0, stream>>>(x, W, a, h, s1, s2, u, uq, e2, eq2);
  k_sortz<<<2 * B, 256, 0, stream>>>(s1, s2, u, uq, e2, eq2, A, Bc, s2s, idx2);
  k_scan1<<<B * 16, 256, 0, stream>>>(A, Bc, h, idx2, ctA, ctB);
  k_scan2<<<B * 16, 256, 0, stream>>>(A, Bc, h, idx2, ctA, ctB, SA, PB);
  k_out<<<B * N / 4, 256, 0, stream>>>(s1, u, uq, s2s, SA, PB, out);
}

// Round 5
// 63.255 us; speedup vs baseline: 2.0568x; 2.0568x over previous
//
#include <hip/hip_runtime.h>
#include <math.h>

#define B 8
#define N 2048
#define NP1 2049
#define K 2048
#define KP1 2049
#define FIN 128
#define FOUT 64
#define NS 0.2f
#define NCH 64
#define CHS 32

// monotone bucket map: bucket(x) < bucket(t) => x < t ; bucket(x) > bucket(t) => x >= t
__device__ __forceinline__ int bucketOf(float v) {
  int q = (int)floorf((v + 8.0f) * 128.0f);   // K=2048 over [-8,8]
  return min(max(q, 0), K - 1);
}

__device__ __forceinline__ int wscan_add_i(int v, int lane) {
#pragma unroll
  for (int off = 1; off < 64; off <<= 1) {
    int o = __shfl_up(v, off, 64);
    v += (lane >= off) ? o : 0;
  }
  return v;
}
__device__ __forceinline__ float wscan_add_f(float v, int lane) {
#pragma unroll
  for (int off = 1; off < 64; off <<= 1) {
    float o = __shfl_up(v, off, 64);
    v += (lane >= off) ? o : 0.f;
  }
  return v;
}

// ---------------------------------------------------------------------------
// KA: h = x@W, s1 = h.a1, s2 = h.a2, exps. (same as round 4)
// ---------------------------------------------------------------------------
#define RPB 32
__global__ __launch_bounds__(256, 2) void k_hs(
    const float* __restrict__ x, const float* __restrict__ W,
    const float* __restrict__ a, float* __restrict__ h,
    float* __restrict__ s1, float* __restrict__ s2,
    float* __restrict__ u, float* __restrict__ uq,
    float* __restrict__ e2, float* __restrict__ eq2) {
  __shared__ float xs[RPB * FIN];  // 16 KB
  const int row0 = blockIdx.x * RPB;
  const int lane = threadIdx.x & 63;
  const int wv = threadIdx.x >> 6;

  {
    const float4* src = (const float4*)(x + (size_t)row0 * FIN);
    float4* dst = (float4*)xs;
#pragma unroll
    for (int t = 0; t < 4; ++t)
      dst[threadIdx.x + 256 * t] = src[threadIdx.x + 256 * t];
  }

  float w[FIN];
#pragma unroll
  for (int k = 0; k < FIN; ++k) w[k] = W[k * FOUT + lane];
  const float a1 = a[lane];
  const float a2 = a[FOUT + lane];
  __syncthreads();

  for (int n = 0; n < 8; ++n) {
    const int r = wv * 8 + n;
    const float* xr = xs + r * FIN;
    float ac0 = 0.f, ac1 = 0.f, ac2 = 0.f, ac3 = 0.f;
#pragma unroll
    for (int k4 = 0; k4 < FIN; k4 += 4) {
      float4 xv = *(const float4*)(xr + k4);
      ac0 = fmaf(xv.x, w[k4 + 0], ac0);
      ac1 = fmaf(xv.y, w[k4 + 1], ac1);
      ac2 = fmaf(xv.z, w[k4 + 2], ac2);
      ac3 = fmaf(xv.w, w[k4 + 3], ac3);
    }
    const float acc = (ac0 + ac1) + (ac2 + ac3);
    const int row = row0 + r;
    h[(size_t)row * FOUT + lane] = acc;

    float v1 = acc * a1;
    float v2 = acc * a2;
#pragma unroll
    for (int off = 32; off > 0; off >>= 1) {
      v1 += __shfl_xor(v1, off, 64);
      v2 += __shfl_xor(v2, off, 64);
    }
    if (lane == 0) {
      s1[row] = v1;
      s2[row] = v2;
      u[row] = expf(v1);
      uq[row] = expf(NS * v1);
      e2[row] = expf(v2);
      eq2[row] = expf(NS * v2);
    }
  }
}

// ---------------------------------------------------------------------------
// KB: counting-sort bucketing. grid = 2*B blocks x 1024 threads.
// type 0 (s1): bucket-order elemS1/elemU/elemUq, start1, slot-prefix of u,uq.
// type 1 (s2): bucket-order elemS2/idx2, start2.
// ~6 barriers total (vs 66 for bitonic).
// ---------------------------------------------------------------------------
__global__ __launch_bounds__(1024) void k_bucket(
    const float* __restrict__ s1, const float* __restrict__ s2,
    const float* __restrict__ u, const float* __restrict__ uq,
    int* __restrict__ start1, float* __restrict__ elemS1,
    float* __restrict__ elemU, float* __restrict__ elemUq,
    float* __restrict__ slotPrefU, float* __restrict__ slotPrefQ,
    int* __restrict__ start2, float* __restrict__ elemS2,
    int* __restrict__ idx2) {
  __shared__ int cnt[K];     // becomes exclusive bucket-start after scan
  __shared__ int cur[K];
  __shared__ float eS[N], eU[N], eQ[N];
  __shared__ int eJ[N];
  __shared__ int wt[16];
  __shared__ float wtU[16], wtQ[16];

  const int type = blockIdx.x & 1;
  const int b = blockIdx.x >> 1;
  const int tid = threadIdx.x;
  const int lane = tid & 63;
  const int wv = tid >> 6;
  const float* key = (type ? s2 : s1) + b * N;

  cnt[tid] = 0; cnt[tid + 1024] = 0;
  __syncthreads();
  const float k0 = key[tid], k1 = key[tid + 1024];
  const int q0 = bucketOf(k0), q1 = bucketOf(k1);
  atomicAdd(&cnt[q0], 1);
  atomicAdd(&cnt[q1], 1);
  __syncthreads();

  // exclusive scan of cnt[2048] (2 entries/thread, shfl wave-scan)
  const int c0 = cnt[2 * tid], c1 = cnt[2 * tid + 1];
  const int loc = c0 + c1;
  const int incl = wscan_add_i(loc, lane);
  if (lane == 63) wt[wv] = incl;
  __syncthreads();
  int cross = 0;
#pragma unroll
  for (int w2 = 0; w2 < 16; ++w2) cross += (w2 < wv) ? wt[w2] : 0;
  const int ex = cross + incl - loc;
  cnt[2 * tid] = ex;       cnt[2 * tid + 1] = ex + c0;
  cur[2 * tid] = ex;       cur[2 * tid + 1] = ex + c0;
  __syncthreads();

  // scatter (intra-bucket order arbitrary -- only ulp-level fp reassociation)
  {
    int slot = atomicAdd(&cur[q0], 1);
    if (type == 0) { eS[slot] = k0; eU[slot] = u[b * N + tid]; eQ[slot] = uq[b * N + tid]; }
    else           { eS[slot] = k0; eJ[slot] = tid; }
    slot = atomicAdd(&cur[q1], 1);
    if (type == 0) { eS[slot] = k1; eU[slot] = u[b * N + tid + 1024]; eQ[slot] = uq[b * N + tid + 1024]; }
    else           { eS[slot] = k1; eJ[slot] = tid + 1024; }
  }
  __syncthreads();

  if (type == 1) {
    elemS2[b * N + tid] = eS[tid];  elemS2[b * N + tid + 1024] = eS[tid + 1024];
    idx2[b * N + tid] = eJ[tid];    idx2[b * N + tid + 1024] = eJ[tid + 1024];
    start2[b * KP1 + tid] = cnt[tid];  start2[b * KP1 + tid + 1024] = cnt[tid + 1024];
    if (tid == 0) start2[b * KP1 + K] = N;
    return;
  }
  elemS1[b * N + tid] = eS[tid];  elemS1[b * N + tid + 1024] = eS[tid + 1024];
  elemU[b * N + tid] = eU[tid];   elemU[b * N + tid + 1024] = eU[tid + 1024];
  elemUq[b * N + tid] = eQ[tid];  elemUq[b * N + tid + 1024] = eQ[tid + 1024];
  start1[b * KP1 + tid] = cnt[tid];  start1[b * KP1 + tid + 1024] = cnt[tid + 1024];
  if (tid == 0) start1[b * KP1 + K] = N;

  // exclusive slot-prefix of eU, eQ (2048 each)
  const float u0 = eU[2 * tid], u1 = eU[2 * tid + 1];
  const float g0 = eQ[2 * tid], g1 = eQ[2 * tid + 1];
  const float locU = u0 + u1, locQ = g0 + g1;
  const float iU = wscan_add_f(locU, lane);
  const float iQ = wscan_add_f(locQ, lane);
  if (lane == 63) { wtU[wv] = iU; wtQ[wv] = iQ; }
  __syncthreads();
  float crU = 0.f, crQ = 0.f, totU = 0.f, totQ = 0.f;
#pragma unroll
  for (int w2 = 0; w2 < 16; ++w2) {
    const float au = wtU[w2], aq = wtQ[w2];
    crU += (w2 < wv) ? au : 0.f;
    crQ += (w2 < wv) ? aq : 0.f;
    totU += au; totQ += aq;
  }
  const float exU = crU + iU - locU, exQ = crQ + iQ - locQ;
  slotPrefU[b * NP1 + 2 * tid] = exU;  slotPrefU[b * NP1 + 2 * tid + 1] = exU + u0;
  slotPrefQ[b * NP1 + 2 * tid] = exQ;  slotPrefQ[b * NP1 + 2 * tid + 1] = exQ + g0;
  if (tid == 0) { slotPrefU[b * NP1 + N] = totU; slotPrefQ[b * NP1 + N] = totQ; }
}

// ---------------------------------------------------------------------------
// KC: per s2-slot s: Z via bucket-prefix + exact boundary sweep of one bucket;
//     Aslot[s] = e2_j/Z, Bslot[s] = eq2_j/Z.  grid = B*N/256 x 256
// ---------------------------------------------------------------------------
__global__ void k_z(const float* __restrict__ elemS1, const float* __restrict__ elemU,
                    const float* __restrict__ elemUq, const float* __restrict__ slotPrefU,
                    const float* __restrict__ slotPrefQ, const int* __restrict__ start1,
                    const float* __restrict__ elemS2, const int* __restrict__ idx2,
                    const float* __restrict__ e2, const float* __restrict__ eq2,
                    float* __restrict__ Aslot, float* __restrict__ Bslot) {
  const int g = blockIdx.x * 256 + threadIdx.x;
  const int b = g >> 11;
  const int s = g & (N - 1);
  const float t = -elemS2[b * N + s];
  const int j = idx2[b * N + s];
  const int q = bucketOf(t);
  const int sb = start1[b * KP1 + q], se = start1[b * KP1 + q + 1];
  float PuC = slotPrefU[b * NP1 + sb];
  float PqC = slotPrefQ[b * NP1 + sb];
  for (int s2i = sb; s2i < se; ++s2i) {
    const bool lt = elemS1[b * N + s2i] < t;
    PuC += lt ? elemU[b * N + s2i] : 0.f;
    PqC += lt ? elemUq[b * N + s2i] : 0.f;
  }
  const float totU = slotPrefU[b * NP1 + N];
  const float SU = totU - PuC;
  const float E = e2[b * N + j], Eq = eq2[b * N + j];
  const float Z = E * SU + Eq * PqC;
  Aslot[b * N + s] = E / Z;
  Bslot[b * N + s] = Eq / Z;
}

// ---------------------------------------------------------------------------
// KD: chunk totals of A*h, B*h in slot order. wave = chunk of 32.
// grid = B*16 x 256.
// ---------------------------------------------------------------------------
__global__ void k_scan1(const float* __restrict__ Aslot, const float* __restrict__ Bslot,
                        const float* __restrict__ h, const int* __restrict__ idx2,
                        float* __restrict__ ctA, float* __restrict__ ctB) {
  const int b = blockIdx.x >> 4;
  const int chunk = (blockIdx.x & 15) * 4 + (threadIdx.x >> 6);
  const int f = threadIdx.x & 63;
  float ta = 0.f, tb = 0.f;
#pragma unroll 4
  for (int rr = 0; rr < CHS; ++rr) {
    const int r = chunk * CHS + rr;
    const int j = idx2[b * N + r];
    const float hv = h[((size_t)b * N + j) * FOUT + f];
    ta = fmaf(Aslot[b * N + r], hv, ta);
    tb = fmaf(Bslot[b * N + r], hv, tb);
  }
  ctA[(b * NCH + chunk) * FOUT + f] = ta;
  ctB[(b * NCH + chunk) * FOUT + f] = tb;
}

// ---------------------------------------------------------------------------
// KE: PB[s][f] = prefix over slots < s of B*h; SA[s][f] = suffix over >= s.
// grid = B*16 x 256, chunk totals staged in LDS.
// ---------------------------------------------------------------------------
__global__ void k_scan2(const float* __restrict__ Aslot, const float* __restrict__ Bslot,
                        const float* __restrict__ h, const int* __restrict__ idx2,
                        const float* __restrict__ ctA, const float* __restrict__ ctB,
                        float* __restrict__ SA, float* __restrict__ PB) {
  __shared__ float cA[NCH * FOUT];
  __shared__ float cB[NCH * FOUT];
  const int b = blockIdx.x >> 4;
  const int chunk = (blockIdx.x & 15) * 4 + (threadIdx.x >> 6);
  const int f = threadIdx.x & 63;

  for (int t = threadIdx.x; t < NCH * FOUT; t += 256) {
    cA[t] = ctA[b * NCH * FOUT + t];
    cB[t] = ctB[b * NCH * FOUT + t];
  }
  __syncthreads();

  float offA = 0.f, offB = 0.f;
#pragma unroll 8
  for (int c2 = 0; c2 < NCH; ++c2) {
    const float va = cA[c2 * FOUT + f];
    const float vb = cB[c2 * FOUT + f];
    if (c2 > chunk) offA += va;
    if (c2 < chunk) offB += vb;
  }

  float run = offB;
  for (int rr = 0; rr < CHS; ++rr) {
    const int r = chunk * CHS + rr;
    const int j = idx2[b * N + r];
    const float hv = h[((size_t)b * N + j) * FOUT + f];
    run = fmaf(Bslot[b * N + r], hv, run);
    PB[((size_t)b * NP1 + r + 1) * FOUT + f] = run;
  }
  run = offA;
  for (int rr = CHS - 1; rr >= 0; --rr) {
    const int r = chunk * CHS + rr;
    const int j = idx2[b * N + r];
    const float hv = h[((size_t)b * N + j) * FOUT + f];
    run = fmaf(Aslot[b * N + r], hv, run);
    SA[((size_t)b * NP1 + r) * FOUT + f] = run;
  }
  if (chunk == 0) {
    PB[((size_t)b * NP1 + 0) * FOUT + f] = 0.f;
    SA[((size_t)b * NP1 + N) * FOUT + f] = 0.f;
  }
}

// ---------------------------------------------------------------------------
// KF: per row i (one wave): q = bucket(-s1_i); base sums at bucket edges +
//     exact boundary sweep of bucket q; out = lrelu(u*SA + uq*PB).
// grid = B*N/4 x 256.
// ---------------------------------------------------------------------------
__global__ void k_out(const float* __restrict__ s1r, const float* __restrict__ u,
                      const float* __restrict__ uq, const int* __restrict__ start2,
                      const float* __restrict__ elemS2, const int* __restrict__ idx2,
                      const float* __restrict__ Aslot, const float* __restrict__ Bslot,
                      const float* __restrict__ h, const float* __restrict__ SA,
                      const float* __restrict__ PB, float* __restrict__ out) {
  const int wv = threadIdx.x >> 6;
  const int lane = threadIdx.x & 63;
  const int row = blockIdx.x * 4 + wv;
  const int b = row >> 11;
  const float t = -s1r[row];
  const int q = bucketOf(t);
  const int sb = start2[b * KP1 + q], se = start2[b * KP1 + q + 1];

  float sa = SA[((size_t)b * NP1 + se) * FOUT + lane];  // buckets > q
  float pb = PB[((size_t)b * NP1 + sb) * FOUT + lane];  // buckets < q
  for (int s = sb; s < se; ++s) {
    const float s2v = elemS2[b * N + s];
    const int j = idx2[b * N + s];
    const float hv = h[((size_t)b * N + j) * FOUT + lane];
    if (s2v >= t) sa = fmaf(Aslot[b * N + s], hv, sa);
    else          pb = fmaf(Bslot[b * N + s], hv, pb);
  }
  const float v = u[row] * sa + uq[row] * pb;
  out[(size_t)row * FOUT + lane] = v >= 0.f ? v : NS * v;
}

extern "C" void kernel_launch(void* const* d_in, const int* in_sizes, int n_in,
                              void* d_out, int out_size, void* d_ws, size_t ws_size,
                              hipStream_t stream) {
  const float* x = (const float*)d_in[0];   // (8,2048,128)
  const float* W = (const float*)d_in[1];   // (128,64)
  const float* a = (const float*)d_in[2];   // (128,1)
  float* out = (float*)d_out;               // (8,2048,64)

  float* ws = (float*)d_ws;
  float* h = ws;                        // B*N*FOUT (k_out reads h -> no alias with out)
  float* s1 = h + (size_t)B * N * FOUT; // B*N each
  float* s2 = s1 + B * N;
  float* u = s2 + B * N;
  float* uq = u + B * N;
  float* e2 = uq + B * N;
  float* eq2 = e2 + B * N;
  float* elemS1 = eq2 + B * N;
  float* elemU = elemS1 + B * N;
  float* elemUq = elemU + B * N;
  float* elemS2 = elemUq + B * N;
  float* Aslot = elemS2 + B * N;
  float* Bslot = Aslot + B * N;
  float* slotPrefU = Bslot + B * N;     // B*NP1
  float* slotPrefQ = slotPrefU + B * NP1;
  int* idx2 = (int*)(slotPrefQ + B * NP1);   // B*N
  int* start1 = idx2 + B * N;                // B*KP1
  int* start2 = start1 + B * KP1;
  float* ctA = (float*)(start2 + B * KP1);   // B*64*64
  float* ctB = ctA + B * NCH * FOUT;
  float* SA = ctB + B * NCH * FOUT;          // B*NP1*64
  float* PB = SA + (size_t)B * NP1 * FOUT;

  k_hs<<<B * N / RPB, 256, 0, stream>>>(x, W, a, h, s1, s2, u, uq, e2, eq2);
  k_bucket<<<2 * B, 1024, 0, stream>>>(s1, s2, u, uq, start1, elemS1, elemU, elemUq,
                                       slotPrefU, slotPrefQ, start2, elemS2, idx2);
  k_z<<<B * (N / 256), 256, 0, stream>>>(elemS1, elemU, elemUq, slotPrefU, slotPrefQ,
                                         start1, elemS2, idx2, e2, eq2, Aslot, Bslot);
  k_scan1<<<B * 16, 256, 0, stream>>>(Aslot, Bslot, h, idx2, ctA, ctB);
  k_scan2<<<B * 16, 256, 0, stream>>>(Aslot, Bslot, h, idx2, ctA, ctB, SA, PB);
  k_out<<<B * N / 4, 256, 0, stream>>>(s1, u, uq, start2, elemS2, idx2, Aslot, Bslot,
                                       h, SA, PB, out);
}